// Round 1
// baseline (3556.806 us; speedup 1.0000x reference)
//
#include <hip/hip_runtime.h>

#define NEG_SLOPE 0.1f

static inline int cdiv(int a, int b) { return (a + b - 1) / b; }

// Compile-time geometry: interior rectangle (no bounds checks needed) vs edge ring.
template <int K, int S, int PAD, int HIN, int WIN, int HOUT, int WOUT, int TW>
struct Geom {
    static constexpr int SLOTS_W = WOUT / TW;       // thread-slots per output row
    static constexpr int NSLOT   = HOUT * SLOTS_W;  // slots per (b, co_group) plane
    static constexpr int L       = (TW - 1) * S + K;
    // interior rows: ho*S-PAD >= 0  and  ho*S-PAD+K <= HIN
    static constexpr int HO_LO   = (PAD + S - 1) / S;
    static constexpr int HO_HI0  = (HIN - K + PAD) / S + 1;
    static constexpr int HO_HI   = HO_HI0 < HOUT ? HO_HI0 : HOUT;
    // interior col-slots: ws*TW*S-PAD >= 0  and  ws*TW*S-PAD+L <= WIN
    static constexpr int WS_LO   = (PAD + TW * S - 1) / (TW * S);
    static constexpr int WS_HI0  = (WIN + PAD - L) / (TW * S) + 1;
    static constexpr int WS_HI   = WS_HI0 < SLOTS_W ? WS_HI0 : SLOTS_W;
    static constexpr int WS_N    = WS_HI - WS_LO;
    static constexpr int N_INT   = (HO_HI - HO_LO) * WS_N;
    static constexpr int N_EDGE  = NSLOT - N_INT;
};

// ---------------- interior conv + leaky relu (no bounds checks at all) ----------------
template <int K, int S, int PAD, int CIN, int COUT,
          int HIN, int WIN, int HOUT, int WOUT, int TCO, int TW>
__global__ __launch_bounds__(256, 4) void conv_int(const float* __restrict__ x,
                                                   const float* __restrict__ w,
                                                   const float* __restrict__ bs,
                                                   float* __restrict__ y) {
    using G = Geom<K, S, PAD, HIN, WIN, HOUT, WOUT, TW>;
    constexpr int NW = TCO * CIN * K * K;

    __shared__ float wlds[NW];

    const int zz  = blockIdx.z;
    const int b   = zz / (COUT / TCO);
    const int cob = (zz % (COUT / TCO)) * TCO;

    // stage weights: wlds[((ci*K+kh)*K+kw)*TCO + t] = w[(cob+t)][ci][kh][kw]
    for (int i = threadIdx.x; i < NW; i += 256) {
        int t    = i % TCO;
        int rest = i / TCO;
        wlds[i] = w[(size_t)(cob + t) * (CIN * K * K) + rest];
    }
    __syncthreads();

    const int s = blockIdx.x * 256 + threadIdx.x;
    if (s >= G::N_INT) return;

    const int ho = G::HO_LO + s / G::WS_N;
    const int wo = (G::WS_LO + s % G::WS_N) * TW;

    const float* xb = x + (size_t)b * CIN * HIN * WIN;

    float acc[TCO][TW];
#pragma unroll
    for (int t = 0; t < TCO; ++t) {
        float bv = bs[cob + t];
#pragma unroll
        for (int j = 0; j < TW; ++j) acc[t][j] = bv;
    }

    const int hi0 = ho * S - PAD;
    const int wi0 = wo * S - PAD;

#pragma unroll 1
    for (int ci = 0; ci < CIN; ++ci) {
        const float* xc = xb + (size_t)ci * HIN * WIN;
        const float* wc = &wlds[(ci * K * K) * TCO];
#pragma unroll
        for (int kh = 0; kh < K; ++kh) {
            const float* xr = xc + (size_t)(hi0 + kh) * WIN + wi0;
            float r[G::L];
#pragma unroll
            for (int u = 0; u < G::L; ++u) r[u] = xr[u];
#pragma unroll
            for (int kw = 0; kw < K; ++kw) {
                const float* wg = wc + (kh * K + kw) * TCO;
                float w8[TCO];
#pragma unroll
                for (int t = 0; t < TCO; ++t) w8[t] = wg[t];
#pragma unroll
                for (int j = 0; j < TW; ++j) {
                    const float xv = r[kw + j * S];
#pragma unroll
                    for (int t = 0; t < TCO; ++t)
                        acc[t][j] = fmaf(xv, w8[t], acc[t][j]);
                }
            }
        }
    }

#pragma unroll
    for (int t = 0; t < TCO; ++t) {
        float* yr = y + (((size_t)b * COUT + cob + t) * HOUT + ho) * WOUT + wo;
#pragma unroll
        for (int j = 0; j < TW; ++j) {
            const float v = acc[t][j];
            yr[j] = v >= 0.0f ? v : NEG_SLOPE * v;
        }
    }
}

// ---------------- edge conv + leaky relu (clamped loads, tiny work) ----------------
template <int K, int S, int PAD, int CIN, int COUT,
          int HIN, int WIN, int HOUT, int WOUT, int TCO, int TW>
__global__ __launch_bounds__(256) void conv_edge(const float* __restrict__ x,
                                                 const float* __restrict__ w,
                                                 const float* __restrict__ bs,
                                                 float* __restrict__ y) {
    using G = Geom<K, S, PAD, HIN, WIN, HOUT, WOUT, TW>;
    constexpr int SLOTS_W = G::SLOTS_W;
    constexpr int NW = TCO * CIN * K * K;

    __shared__ float wlds[NW];

    const int zz  = blockIdx.z;
    const int b   = zz / (COUT / TCO);
    const int cob = (zz % (COUT / TCO)) * TCO;

    for (int i = threadIdx.x; i < NW; i += 256) {
        int t    = i % TCO;
        int rest = i / TCO;
        wlds[i] = w[(size_t)(cob + t) * (CIN * K * K) + rest];
    }
    __syncthreads();

    const int s = blockIdx.x * 256 + threadIdx.x;
    if (s >= G::N_EDGE) return;

    // edge ring = top rows + bottom rows + left strip + right strip
    constexpr int TOPN = G::HO_LO * SLOTS_W;
    constexpr int BOTN = (HOUT - G::HO_HI) * SLOTS_W;
    constexpr int MIDH = G::HO_HI - G::HO_LO;
    constexpr int LW   = G::WS_LO;
    constexpr int RW   = SLOTS_W - G::WS_HI;
    constexpr int LN   = MIDH * LW;

    int ho = 0, ws = 0;
    if (s < TOPN) {
        ho = s / SLOTS_W;
        ws = s % SLOTS_W;
    } else if (s < TOPN + BOTN) {
        int t = s - TOPN;
        ho = G::HO_HI + t / SLOTS_W;
        ws = t % SLOTS_W;
    } else if (s < TOPN + BOTN + LN) {
        int t = s - TOPN - BOTN;
        constexpr int D = LW > 0 ? LW : 1;
        ho = G::HO_LO + t / D;
        ws = t % D;
    } else {
        int t = s - TOPN - BOTN - LN;
        constexpr int D = RW > 0 ? RW : 1;
        ho = G::HO_LO + t / D;
        ws = G::WS_HI + t % D;
    }
    const int wo = ws * TW;

    const float* xb = x + (size_t)b * CIN * HIN * WIN;

    float acc[TCO][TW];
#pragma unroll
    for (int t = 0; t < TCO; ++t) {
        float bv = bs[cob + t];
#pragma unroll
        for (int j = 0; j < TW; ++j) acc[t][j] = bv;
    }

    const int hi0 = ho * S - PAD;
    const int wi0 = wo * S - PAD;

#pragma unroll 1
    for (int ci = 0; ci < CIN; ++ci) {
        const float* xc = xb + (size_t)ci * HIN * WIN;
        const float* wc = &wlds[(ci * K * K) * TCO];
#pragma unroll
        for (int kh = 0; kh < K; ++kh) {
            const int hi = hi0 + kh;
            const bool rowok = (unsigned)hi < (unsigned)HIN;
            const float* xr = xc + (size_t)(rowok ? hi : 0) * WIN;
            float r[G::L];
#pragma unroll
            for (int u = 0; u < G::L; ++u) {
                const int wi = wi0 + u;
                const bool ok = rowok && (unsigned)wi < (unsigned)WIN;
                const float v = xr[ok ? wi : 0];
                r[u] = ok ? v : 0.0f;
            }
#pragma unroll
            for (int kw = 0; kw < K; ++kw) {
                const float* wg = wc + (kh * K + kw) * TCO;
                float w8[TCO];
#pragma unroll
                for (int t = 0; t < TCO; ++t) w8[t] = wg[t];
#pragma unroll
                for (int j = 0; j < TW; ++j) {
                    const float xv = r[kw + j * S];
#pragma unroll
                    for (int t = 0; t < TCO; ++t)
                        acc[t][j] = fmaf(xv, w8[t], acc[t][j]);
                }
            }
        }
    }

#pragma unroll
    for (int t = 0; t < TCO; ++t) {
        float* yr = y + (((size_t)b * COUT + cob + t) * HOUT + ho) * WOUT + wo;
#pragma unroll
        for (int j = 0; j < TW; ++j) {
            const float v = acc[t][j];
            yr[j] = v >= 0.0f ? v : NEG_SLOPE * v;
        }
    }
}

// ---------------- bilinear warp (B=4, H=12, W=24) ----------------
__global__ void warp_kernel(const float* __restrict__ img, const float* __restrict__ flow,
                            float* __restrict__ out, int C) {
    const int H = 12, W = 24, HW = 288;
    int idx = blockIdx.x * blockDim.x + threadIdx.x;
    int total = 4 * C * HW;
    if (idx >= total) return;
    int w = idx % W;
    int h = (idx / W) % H;
    int c = (idx / HW) % C;
    int b = idx / (HW * C);

    float fx = flow[(((size_t)b * 2 + 0) * H + h) * W + w] * 0.625f;
    float fy = flow[(((size_t)b * 2 + 1) * H + h) * W + w] * 0.625f;
    float px = (float)w + fx;
    float py = (float)h + fy;
    float x0f = floorf(px);
    float y0f = floorf(py);
    float wx = px - x0f;
    float wy = py - y0f;
    int x0 = (int)x0f;
    int y0 = (int)y0f;

    const float* ip = img + ((size_t)b * C + c) * HW;
    auto g = [&](int yi, int xi) -> float {
        if (xi < 0 || xi > W - 1 || yi < 0 || yi > H - 1) return 0.0f;
        return ip[yi * W + xi];
    };
    float v = g(y0, x0) * (1.0f - wx) * (1.0f - wy)
            + g(y0, x0 + 1) * wx * (1.0f - wy)
            + g(y0 + 1, x0) * (1.0f - wx) * wy
            + g(y0 + 1, x0 + 1) * wx * wy;
    out[idx] = v;
}

// ---------------- correlation (7x7 disp) + lrelu ----------------
__global__ void corr_lrelu(const float* __restrict__ f1, const float* __restrict__ wp,
                           float* __restrict__ out, int C) {
    const int H = 12, W = 24, HW = 288;
    int idx = blockIdx.x * blockDim.x + threadIdx.x;
    int total = 4 * 49 * HW;
    if (idx >= total) return;
    int w = idx % W;
    int h = (idx / W) % H;
    int d = (idx / HW) % 49;
    int b = idx / (49 * HW);
    int di = d / 7 - 3;
    int dj = d % 7 - 3;
    int h2 = h + di;
    int w2 = w + dj;

    float s = 0.0f;
    if (h2 >= 0 && h2 < H && w2 >= 0 && w2 < W) {
        const float* a = f1 + (size_t)b * C * HW + h * W + w;
        const float* p = wp + (size_t)b * C * HW + h2 * W + w2;
        for (int c = 0; c < C; ++c) s = fmaf(a[(size_t)c * HW], p[(size_t)c * HW], s);
    }
    s /= (float)C;
    s = (s >= 0.0f) ? s : NEG_SLOPE * s;
    out[idx] = s;
}

// ---------------- host ----------------
template <int K, int S, int PAD, int CIN, int COUT,
          int HIN, int WIN, int HOUT, int WOUT, int TCO, int TW>
static void launch_conv(const float* x, const float* w, const float* bs, float* y,
                        hipStream_t stream) {
    using G = Geom<K, S, PAD, HIN, WIN, HOUT, WOUT, TW>;
    const int z = 4 * (COUT / TCO);
    if (G::N_INT > 0)
        conv_int<K, S, PAD, CIN, COUT, HIN, WIN, HOUT, WOUT, TCO, TW>
            <<<dim3(cdiv(G::N_INT, 256), 1, z), 256, 0, stream>>>(x, w, bs, y);
    if (G::N_EDGE > 0)
        conv_edge<K, S, PAD, CIN, COUT, HIN, WIN, HOUT, WOUT, TCO, TW>
            <<<dim3(cdiv(G::N_EDGE, 256), 1, z), 256, 0, stream>>>(x, w, bs, y);
}

extern "C" void kernel_launch(void* const* d_in, const int* in_sizes, int n_in,
                              void* d_out, int out_size, void* d_ws, size_t ws_size,
                              hipStream_t stream) {
    const float* img1 = (const float*)d_in[0];
    const float* img2 = (const float*)d_in[1];
    const float* flow = (const float*)d_in[2];
    float* out = (float*)d_out;

    const float* W[10];
    const float* Bs[10];
    for (int l = 0; l < 10; ++l) {
        W[l]  = (const float*)d_in[3 + 2 * l];
        Bs[l] = (const float*)d_in[4 + 2 * l];
    }

    // ws layout identical to the proven footprint (47.85M floats = 191.4 MB)
    float* ws = (float*)d_ws;
    size_t off = 0;
    float* bufA = ws + off; off += 37748736;  // 4*32*384*768
    float* bufB = ws + off; off += 9437184;   // 4*32*192*384
    float* f1   = ws + off; off += 221184;    // 4*192*12*24
    float* f2   = ws + off; off += 221184;
    float* wrp  = ws + off; off += 221184;

    auto chain = [&](const float* img, float* fout) {
        // L1: 3->32, 7x7 s1 p3, 384x768
        launch_conv<7,1,3,  3, 32, 384,768, 384,768, 8,4>(img,  W[0], Bs[0], bufA, stream);
        // L2: 32->32, 3x3 s2 p1 -> 192x384
        launch_conv<3,2,1, 32, 32, 384,768, 192,384, 8,4>(bufA, W[1], Bs[1], bufB, stream);
        // L3: 32->32, s1
        launch_conv<3,1,1, 32, 32, 192,384, 192,384, 8,4>(bufB, W[2], Bs[2], bufA, stream);
        // L4: 32->32, s1
        launch_conv<3,1,1, 32, 32, 192,384, 192,384, 8,4>(bufA, W[3], Bs[3], bufB, stream);
        // L5: 32->64, s2 -> 96x192
        launch_conv<3,2,1, 32, 64, 192,384,  96,192, 8,4>(bufB, W[4], Bs[4], bufA, stream);
        // L6: 64->64, s1
        launch_conv<3,1,1, 64, 64,  96,192,  96,192, 8,4>(bufA, W[5], Bs[5], bufB, stream);
        // L7: 64->96, s2 -> 48x96   (TCO=4: more waves for latency-bound tail layers)
        launch_conv<3,2,1, 64, 96,  96,192,  48, 96, 4,4>(bufB, W[6], Bs[6], bufA, stream);
        // L8: 96->96, s1
        launch_conv<3,1,1, 96, 96,  48, 96,  48, 96, 4,4>(bufA, W[7], Bs[7], bufB, stream);
        // L9: 96->128, s2 -> 24x48
        launch_conv<3,2,1, 96,128,  48, 96,  24, 48, 4,4>(bufB, W[8], Bs[8], bufA, stream);
        // L10: 128->192, s2 -> 12x24 (TW=2 so the 12x24 plane fills blocks)
        launch_conv<3,2,1,128,192,  24, 48,  12, 24, 4,2>(bufA, W[9], Bs[9], fout, stream);
    };

    chain(img1, f1);
    chain(img2, f2);

    warp_kernel<<<cdiv(4 * 192 * 288, 256), 256, 0, stream>>>(f2, flow, wrp, 192);
    corr_lrelu<<<cdiv(4 * 49 * 288, 256), 256, 0, stream>>>(f1, wrp, out, 192);
}